// Round 16
// baseline (3962.740 us; speedup 1.0000x reference)
//
#include <hip/hip_runtime.h>
#include <stdint.h>

using f32x4  = __attribute__((ext_vector_type(4))) float;
using bf16x8 = __attribute__((ext_vector_type(8))) __bf16;

#define GLOAD_LDS16(src, dst) __builtin_amdgcn_global_load_lds(                 \
    (const __attribute__((address_space(1))) void*)(src),                      \
    (__attribute__((address_space(3))) void*)(dst), 16, 0, 0)

// ===========================================================================
// Fragment-major tile layout for mfma_f32_16x16x32_bf16 (round-4/9 mapping,
// proven conflict-free + correct):
//   128x128 tile = 32 frags f = mi*4 + ks (mi=row/16, ks=k/32).
//   Frag = 64 lanes x 16B; lane (l15,lq) holds T[mi*16+l15][ks*32+lq*8 ..+8].
//   A unit order u = f*64 + lane -> lane's frag is contiguous 16B at u*16:
//   A-fragments load straight global->VGPR (coalesced dwordx4).
//   B tiles HALF-CONTIGUOUS: unit w = h*1024 + g*64 + lane, g = mi*2 + j,
//   ks = 2h + j. B streams through a ring of 4 16KB LDS buffers.
// ===========================================================================

// x (fp32, row-major N x 256) -> actA frag-major bf16 (I=256, NCH=2)
__global__ void cvt_x_kernel(const float* __restrict__ x, __bf16* __restrict__ out) {
    const int u    = blockIdx.x * 256 + threadIdx.x;
    const int lane = u & 63;
    const int f    = (u >> 6) & 31;
    const int c    = (u >> 11) & 1;
    const int rb   = u >> 12;
    const int row  = rb * 128 + ((f >> 2) << 4) + (lane & 15);
    const int i    = c * 128 + ((f & 3) << 5) + ((lane >> 4) << 3);
    const float4 a = *(const float4*)(x + (size_t)row * 256 + i);
    const float4 b = *(const float4*)(x + (size_t)row * 256 + i + 4);
    bf16x8 pv;
    pv[0] = (__bf16)a.x; pv[1] = (__bf16)a.y; pv[2] = (__bf16)a.z; pv[3] = (__bf16)a.w;
    pv[4] = (__bf16)b.x; pv[5] = (__bf16)b.y; pv[6] = (__bf16)b.z; pv[7] = (__bf16)b.w;
    *(bf16x8*)(out + (size_t)u * 8) = pv;
}

// W (R x O x I fp32) -> Bt frag-major bf16, half-contiguous unit order.
template<int I, int O>
__global__ void prep_w_kernel(const float* __restrict__ W, __bf16* __restrict__ Bt) {
    constexpr int NCH = I >> 7;
    const int u    = blockIdx.x * 256 + threadIdx.x;     // < NCH*2048
    const int r    = blockIdx.y;
    const int nb   = blockIdx.z;
    const int lane = u & 63;
    const int g    = (u >> 6) & 15;
    const int h    = (u >> 10) & 1;
    const int c    = u >> 11;
    const int mi   = g >> 1;
    const int ks   = (h << 1) + (g & 1);
    const int row  = nb * 128 + mi * 16 + (lane & 15);
    const int i    = c * 128 + ks * 32 + ((lane >> 4) << 3);
    const float* src = W + ((size_t)r * O + row) * I + i;
    const float4 a = *(const float4*)src;
    const float4 b = *(const float4*)(src + 4);
    bf16x8 pv;
    pv[0] = (__bf16)a.x; pv[1] = (__bf16)a.y; pv[2] = (__bf16)a.z; pv[3] = (__bf16)a.w;
    pv[4] = (__bf16)b.x; pv[5] = (__bf16)b.y; pv[6] = (__bf16)b.z; pv[7] = (__bf16)b.w;
    *(bf16x8*)(Bt + ((((size_t)nb * 9 + r) * NCH + c) * 2048 + (u & 2047)) * 8) = pv;
}

// bias tiles: per nb one 128x64 tile, 16 frags (f = ni*2 + ks2)
template<int O>
__global__ void prep_bias_kernel(const float* __restrict__ b, __bf16* __restrict__ BtB) {
    const int u    = blockIdx.x * 256 + threadIdx.x;     // < (O/128)*1024
    const int nb   = u >> 10;
    const int q    = u & 1023;
    const int lane = q & 63;
    const int f    = q >> 6;
    const int row  = nb * 128 + ((f >> 1) << 4) + (lane & 15);
    const int kb   = ((f & 1) << 5) + ((lane >> 4) << 3);
    bf16x8 pv;
#pragma unroll
    for (int e = 0; e < 8; ++e) {
        const int k = kb + e;
        pv[e] = (k < 9) ? (__bf16)b[(size_t)k * O + row] : (__bf16)0.f;
    }
    *(bf16x8*)(BtB + (size_t)u * 8) = pv;
}

// ---------------------------------------------------------------------------
// Relation-mixed GEMM, r13 skeleton + BV REGISTER PREFETCH + per-h fused fold:
//   y[n,o] = sum_r e[n,r]*(sum_i x[n,i] W[r,o,i]) + sum_r e[n,r] b[r,o]
// Per 128-col i-chunk (18 phases s=2r+h): af[4][4] global->VGPR once;
// prologue stages {0,1,2} + prefetch bv(0) into regs. Phase s: vmcnt(4)
// [stage(s+1) complete for prefetch; stage(s+2) in flight] -> barrier ->
// issue stage(s+3) + ds_read bv(s+1) into off-parity regs -> MFMA with
// bv(s) ALREADY IN REGISTERS (prefetch reads interleave under the cluster)
// -> fused per-h fold acc[m][n] += e_r * t (no acc2; 64 fewer AGPRs, which
// is what makes the prefetch fit where r8 spilled). s=17 needs no wait.
// ---------------------------------------------------------------------------
template<int I, int O, bool RELU, bool OUTF32>
__global__ __launch_bounds__(256, 2)
void kg_gemm(const __bf16* __restrict__ A, const float* __restrict__ E,
             const __bf16* __restrict__ Bt, const __bf16* __restrict__ BtB,
             void* __restrict__ Outv) {
    constexpr int NCH = I >> 7;
    constexpr int NBN = O >> 7;
    static_assert((I & 127) == 0 && (O & 127) == 0, "tile divisibility");

    __shared__ __align__(16) char lds[4 * 16384 + 4608];
    float* const ldsE = (float*)(lds + 65536);   // Et[r][row]

    const int tid  = threadIdx.x;
    const int nwg  = gridDim.x;
    const int braw = blockIdx.x;
    const int bid  = (braw & 7) * (nwg >> 3) + (braw >> 3);   // XCD swizzle (nwg%8==0)
    const int rb   = bid / NBN;
    const int nb   = bid % NBN;
    const int bm0  = rb << 7;
    const int bn0  = nb << 7;
    const int lane = tid & 63;
    const int wid  = tid >> 6;
    const int wr   = (wid >> 1) << 6;
    const int wc   = (wid & 1) << 6;
    const int l15  = lane & 15;
    const int lq   = lane >> 4;

    if (tid < 128) {
        const float* e = E + (size_t)(bm0 + tid) * 9;
#pragma unroll
        for (int q = 0; q < 9; ++q) ldsE[q * 128 + tid] = e[q];
    }
    // drain ldsE writes once; first chunk-top barrier publishes them
    asm volatile("s_waitcnt lgkmcnt(0)" ::: "memory");

    f32x4 acc[4][4];
#pragma unroll
    for (int m = 0; m < 4; ++m)
#pragma unroll
        for (int n = 0; n < 4; ++n)
            acc[m][n] = f32x4{0.f, 0.f, 0.f, 0.f};
    const f32x4 zero4 = {0.f, 0.f, 0.f, 0.f};

    const size_t Abase = (size_t)rb * NCH * 2048;       // units
    const size_t Bbase = (size_t)nb * 9 * NCH * 2048;   // units
    const int afb = (wr >> 4) << 2;   // A frag base
    const int nfb = (wc >> 4) << 1;   // B g base

    // stage sub-phase s (r=s>>1, h=s&1) into buf[s&3]  (4 loads/thread)
    auto stageS = [&](int s, int c) {
        const __bf16* src = Bt + (Bbase + ((size_t)(s >> 1) * NCH + c) * 2048
                                  + (size_t)((s & 1) << 10)) * 8;
        char* dst = lds + ((s & 3) << 14);
#pragma unroll
        for (int it = 0; it < 4; ++it) {
            const int q = it * 256 + tid;
            GLOAD_LDS16(src + (size_t)q * 8, dst + q * 16);
        }
    };
    // read wave's 8 bv fragments of buffer for sub-phase s
    auto readBV = [&](bf16x8 (&bv)[4][2], int s) {
        const char* bp = lds + ((s & 3) << 14);
#pragma unroll
        for (int n = 0; n < 4; ++n)
#pragma unroll
            for (int j = 0; j < 2; ++j)
                bv[n][j] = *(const bf16x8*)(bp + (((nfb + 2 * n + j) << 6) + lane) * 16);
    };

#pragma unroll 1
    for (int c = 0; c < NCH; ++c) {
        // chunk-top barrier: all waves past their last reads of prev chunk
        __builtin_amdgcn_s_barrier();
        __builtin_amdgcn_sched_barrier(0);
        // A fragments: global -> VGPR, once per chunk (oldest vm ops)
        bf16x8 af[4][4];
        {
            const __bf16* Ab = A + (Abase + (size_t)c * 2048) * 8;
#pragma unroll
            for (int m = 0; m < 4; ++m)
#pragma unroll
                for (int ks = 0; ks < 4; ++ks)
                    af[m][ks] = *(const bf16x8*)(Ab + ((size_t)((afb + (m << 2) + ks) << 6) + lane) * 8);
        }
        stageS(0, c); stageS(1, c); stageS(2, c);
        // prologue: bv(0) into regs (af + stage0 complete; stage1,2 in flight)
        bf16x8 bvA[4][2], bvB[4][2];
        asm volatile("s_waitcnt vmcnt(8)" ::: "memory");
        __builtin_amdgcn_s_barrier();
        __builtin_amdgcn_sched_barrier(0);
        readBV(bvA, 0);

#pragma unroll 1
        for (int r = 0; r < 9; ++r) {
            // ---- even phase s = 2r: compute bvA (h=0), prefetch bvB(s+1) ----
            {
                const int s = 2 * r;
                if (s < 16) asm volatile("s_waitcnt vmcnt(4)" ::: "memory");
                else        asm volatile("s_waitcnt vmcnt(0)" ::: "memory");
                __builtin_amdgcn_s_barrier();
                __builtin_amdgcn_sched_barrier(0);
                if (s + 3 <= 17) stageS(s + 3, c);
                readBV(bvB, s + 1);                 // prefetch under MFMA
                f32x4 ev0 = *(const f32x4*)(ldsE + r * 128 + wr + 0  + lq * 4);
                f32x4 ev1 = *(const f32x4*)(ldsE + r * 128 + wr + 16 + lq * 4);
                f32x4 ev2 = *(const f32x4*)(ldsE + r * 128 + wr + 32 + lq * 4);
                f32x4 ev3 = *(const f32x4*)(ldsE + r * 128 + wr + 48 + lq * 4);
#pragma unroll
                for (int n = 0; n < 4; ++n) {
                    f32x4 t0 = __builtin_amdgcn_mfma_f32_16x16x32_bf16(af[0][0], bvA[n][0], zero4, 0, 0, 0);
                    f32x4 t1 = __builtin_amdgcn_mfma_f32_16x16x32_bf16(af[1][0], bvA[n][0], zero4, 0, 0, 0);
                    f32x4 t2 = __builtin_amdgcn_mfma_f32_16x16x32_bf16(af[2][0], bvA[n][0], zero4, 0, 0, 0);
                    f32x4 t3 = __builtin_amdgcn_mfma_f32_16x16x32_bf16(af[3][0], bvA[n][0], zero4, 0, 0, 0);
                    t0 = __builtin_amdgcn_mfma_f32_16x16x32_bf16(af[0][1], bvA[n][1], t0, 0, 0, 0);
                    t1 = __builtin_amdgcn_mfma_f32_16x16x32_bf16(af[1][1], bvA[n][1], t1, 0, 0, 0);
                    t2 = __builtin_amdgcn_mfma_f32_16x16x32_bf16(af[2][1], bvA[n][1], t2, 0, 0, 0);
                    t3 = __builtin_amdgcn_mfma_f32_16x16x32_bf16(af[3][1], bvA[n][1], t3, 0, 0, 0);
#pragma unroll
                    for (int j = 0; j < 4; ++j) {
                        acc[0][n][j] += ev0[j] * t0[j];
                        acc[1][n][j] += ev1[j] * t1[j];
                        acc[2][n][j] += ev2[j] * t2[j];
                        acc[3][n][j] += ev3[j] * t3[j];
                    }
                }
            }
            // ---- odd phase s = 2r+1: compute bvB (h=1), prefetch bvA(s+1) ----
            {
                const int s = 2 * r + 1;
                if (r < 8) {
                    asm volatile("s_waitcnt vmcnt(4)" ::: "memory");
                    __builtin_amdgcn_s_barrier();
                    __builtin_amdgcn_sched_barrier(0);
                    if (s + 3 <= 17) stageS(s + 3, c);
                    readBV(bvA, s + 1);             // prefetch under MFMA
                }
                f32x4 ev0 = *(const f32x4*)(ldsE + r * 128 + wr + 0  + lq * 4);
                f32x4 ev1 = *(const f32x4*)(ldsE + r * 128 + wr + 16 + lq * 4);
                f32x4 ev2 = *(const f32x4*)(ldsE + r * 128 + wr + 32 + lq * 4);
                f32x4 ev3 = *(const f32x4*)(ldsE + r * 128 + wr + 48 + lq * 4);
#pragma unroll
                for (int n = 0; n < 4; ++n) {
                    f32x4 t0 = __builtin_amdgcn_mfma_f32_16x16x32_bf16(af[0][2], bvB[n][0], zero4, 0, 0, 0);
                    f32x4 t1 = __builtin_amdgcn_mfma_f32_16x16x32_bf16(af[1][2], bvB[n][0], zero4, 0, 0, 0);
                    f32x4 t2 = __builtin_amdgcn_mfma_f32_16x16x32_bf16(af[2][2], bvB[n][0], zero4, 0, 0, 0);
                    f32x4 t3 = __builtin_amdgcn_mfma_f32_16x16x32_bf16(af[3][2], bvB[n][0], zero4, 0, 0, 0);
                    t0 = __builtin_amdgcn_mfma_f32_16x16x32_bf16(af[0][3], bvB[n][1], t0, 0, 0, 0);
                    t1 = __builtin_amdgcn_mfma_f32_16x16x32_bf16(af[1][3], bvB[n][1], t1, 0, 0, 0);
                    t2 = __builtin_amdgcn_mfma_f32_16x16x32_bf16(af[2][3], bvB[n][1], t2, 0, 0, 0);
                    t3 = __builtin_amdgcn_mfma_f32_16x16x32_bf16(af[3][3], bvB[n][1], t3, 0, 0, 0);
#pragma unroll
                    for (int j = 0; j < 4; ++j) {
                        acc[0][n][j] += ev0[j] * t0[j];
                        acc[1][n][j] += ev1[j] * t1[j];
                        acc[2][n][j] += ev2[j] * t2[j];
                        acc[3][n][j] += ev3[j] * t3[j];
                    }
                }
            }
        }
    }

    // ---- bias K=64 step: A-cols = e (built from ldsE), B = BtB tile
    __syncthreads();   // full drain; guards buffer overwrite
    {
        char* const bufB = lds;            // 16 KB
        char* const bufA = lds + 16384;    // 16 KB
#pragma unroll
        for (int rr = 0; rr < 4; ++rr) {
            const int q = rr * 256 + tid;
            GLOAD_LDS16(BtB + ((size_t)nb * 1024 + q) * 8, bufB + q * 16);
        }
#pragma unroll
        for (int rr = 0; rr < 4; ++rr) {
            const int q    = rr * 256 + tid;
            const int ln   = q & 63;
            const int f    = q >> 6;                       // ni*2 + ks2
            const int row  = ((f >> 1) << 4) + (ln & 15);
            const int kb   = ((f & 1) << 5) + ((ln >> 4) << 3);
            bf16x8 pv;
#pragma unroll
            for (int e8 = 0; e8 < 8; ++e8) {
                const int k = kb + e8;
                pv[e8] = (k < 9) ? (__bf16)ldsE[k * 128 + row] : (__bf16)0.f;
            }
            *(bf16x8*)(bufA + q * 16) = pv;
        }
        __syncthreads();
#pragma unroll
        for (int ks = 0; ks < 2; ++ks) {
            bf16x8 av[4], bv[4];
#pragma unroll
            for (int m = 0; m < 4; ++m)
                av[m] = *(const bf16x8*)(bufA + (((((wr >> 4) + m) * 2 + ks) << 6) + lane) * 16);
#pragma unroll
            for (int n = 0; n < 4; ++n)
                bv[n] = *(const bf16x8*)(bufB + (((((wc >> 4) + n) * 2 + ks) << 6) + lane) * 16);
#pragma unroll
            for (int m = 0; m < 4; ++m)
#pragma unroll
                for (int n = 0; n < 4; ++n)
                    acc[m][n] = __builtin_amdgcn_mfma_f32_16x16x32_bf16(
                        av[m], bv[n], acc[m][n], 0, 0, 0);
        }
    }

    // ---- epilogue: C/D layout col = l15, row = lq*4 + j
    if (OUTF32) {
        const int orow0 = bm0 + wr + lq * 4;
        const int ocol0 = bn0 + wc + l15;
#pragma unroll
        for (int m = 0; m < 4; ++m)
#pragma unroll
            for (int n = 0; n < 4; ++n)
#pragma unroll
                for (int j = 0; j < 4; ++j) {
                    float v = acc[m][n][j];
                    if (RELU) v = fmaxf(v, 0.f);
                    ((float*)Outv)[(size_t)(orow0 + m * 16 + j) * O + (ocol0 + n * 16)] = v;
                }
    } else {
        // write next layer's A in frag-major (I' = O)
        constexpr int NCHn = O >> 7;
        __bf16* outp = (__bf16*)Outv;
#pragma unroll
        for (int m = 0; m < 4; ++m) {
#pragma unroll
            for (int n = 0; n < 4; ++n) {
                const int col  = bn0 + wc + n * 16 + l15;
                const int c2   = col >> 7;
                const int f2   = (((wr >> 4) + m) << 2) + ((col >> 5) & 3);
                const int ln2  = ((col >> 3) & 3) * 16 + lq * 4;
                const size_t base =
                    (((size_t)rb * NCHn + c2) * 2048 + f2 * 64 + ln2) * 8 + (col & 7);
#pragma unroll
                for (int j = 0; j < 4; ++j) {
                    float v = acc[m][n][j];
                    if (RELU) v = fmaxf(v, 0.f);
                    outp[base + (size_t)j * 8] = (__bf16)v;
                }
            }
        }
    }
}

// ---------------------------------------------------------------------------
extern "C" void kernel_launch(void* const* d_in, const int* in_sizes, int n_in,
                              void* d_out, int out_size, void* d_ws, size_t ws_size,
                              hipStream_t stream) {
    const float* x  = (const float*)d_in[0];
    const float* E  = (const float*)d_in[1];
    const float* W0 = (const float*)d_in[2];
    const float* b0 = (const float*)d_in[3];
    const float* W1 = (const float*)d_in[4];
    const float* b1 = (const float*)d_in[5];
    const float* W2 = (const float*)d_in[6];
    const float* b2 = (const float*)d_in[7];
    const float* W3 = (const float*)d_in[8];
    const float* b3 = (const float*)d_in[9];

    char* ws = (char*)d_ws;
    const size_t actBytes = (size_t)65536 * 512 * 2;           // 64 MiB each
    __bf16* actA = (__bf16*)ws;
    __bf16* actB = (__bf16*)(ws + actBytes);
    char* p = ws + 2 * actBytes;
    __bf16* Bt0 = (__bf16*)p; p += (size_t)4 * 9 * 2 * 2048 * 16;
    __bf16* Bt1 = (__bf16*)p; p += (size_t)4 * 9 * 4 * 2048 * 16;
    __bf16* Bt2 = (__bf16*)p; p += (size_t)4 * 9 * 4 * 2048 * 16;
    __bf16* Bt3 = (__bf16*)p; p += (size_t)2 * 9 * 4 * 2048 * 16;
    __bf16* BtB0 = (__bf16*)p; p += (size_t)4 * 1024 * 16;
    __bf16* BtB1 = (__bf16*)p; p += (size_t)4 * 1024 * 16;
    __bf16* BtB2 = (__bf16*)p; p += (size_t)4 * 1024 * 16;
    __bf16* BtB3 = (__bf16*)p; p += (size_t)2 * 1024 * 16;
    if (ws_size < (size_t)(p - ws)) return;   // ws too small -> visible failure

    // prep (frag-major; Bt half-contiguous)
    cvt_x_kernel<<<dim3(8192), dim3(256), 0, stream>>>(x, actA);
    prep_w_kernel<256, 512><<<dim3(16, 9, 4), dim3(256), 0, stream>>>(W0, Bt0);
    prep_w_kernel<512, 512><<<dim3(32, 9, 4), dim3(256), 0, stream>>>(W1, Bt1);
    prep_w_kernel<512, 512><<<dim3(32, 9, 4), dim3(256), 0, stream>>>(W2, Bt2);
    prep_w_kernel<512, 256><<<dim3(32, 9, 2), dim3(256), 0, stream>>>(W3, Bt3);
    prep_bias_kernel<512><<<dim3(16), dim3(256), 0, stream>>>(b0, BtB0);
    prep_bias_kernel<512><<<dim3(16), dim3(256), 0, stream>>>(b1, BtB1);
    prep_bias_kernel<512><<<dim3(16), dim3(256), 0, stream>>>(b2, BtB2);
    prep_bias_kernel<256><<<dim3(8),  dim3(256), 0, stream>>>(b3, BtB3);

    // 4 fused layers
    kg_gemm<256, 512, true,  false><<<dim3(2048), dim3(256), 0, stream>>>(actA, E, Bt0, BtB0, actB);
    kg_gemm<512, 512, true,  false><<<dim3(2048), dim3(256), 0, stream>>>(actB, E, Bt1, BtB1, actA);
    kg_gemm<512, 512, true,  false><<<dim3(2048), dim3(256), 0, stream>>>(actA, E, Bt2, BtB2, actB);
    kg_gemm<512, 256, false, true ><<<dim3(1024), dim3(256), 0, stream>>>(actB, E, Bt3, BtB3, d_out);
}

// Round 17
// 809.726 us; speedup vs baseline: 4.8939x; 4.8939x over previous
//
#include <hip/hip_runtime.h>
#include <stdint.h>

using f32x4  = __attribute__((ext_vector_type(4))) float;
using bf16x8 = __attribute__((ext_vector_type(8))) __bf16;

#define GLOAD_LDS16(src, dst) __builtin_amdgcn_global_load_lds(                 \
    (const __attribute__((address_space(1))) void*)(src),                      \
    (__attribute__((address_space(3))) void*)(dst), 16, 0, 0)

// ===========================================================================
// Fragment-major tile layout for mfma_f32_16x16x32_bf16 (round-4/9 mapping,
// proven conflict-free + correct):
//   128x128 tile = 32 frags f = mi*4 + ks (mi=row/16, ks=k/32).
//   Frag = 64 lanes x 16B; lane (l15,lq) holds T[mi*16+l15][ks*32+lq*8 ..+8].
//   A unit order u = f*64 + lane -> lane's frag is contiguous 16B at u*16:
//   A-fragments load straight global->VGPR (coalesced dwordx4).
//   B tiles HALF-CONTIGUOUS: unit w = h*1024 + g*64 + lane, g = mi*2 + j,
//   ks = 2h + j. B streams through 4 x 16KB LDS buffers (pair ring).
// ===========================================================================

// x (fp32, row-major N x 256) -> actA frag-major bf16 (I=256, NCH=2)
__global__ void cvt_x_kernel(const float* __restrict__ x, __bf16* __restrict__ out) {
    const int u    = blockIdx.x * 256 + threadIdx.x;
    const int lane = u & 63;
    const int f    = (u >> 6) & 31;
    const int c    = (u >> 11) & 1;
    const int rb   = u >> 12;
    const int row  = rb * 128 + ((f >> 2) << 4) + (lane & 15);
    const int i    = c * 128 + ((f & 3) << 5) + ((lane >> 4) << 3);
    const float4 a = *(const float4*)(x + (size_t)row * 256 + i);
    const float4 b = *(const float4*)(x + (size_t)row * 256 + i + 4);
    bf16x8 pv;
    pv[0] = (__bf16)a.x; pv[1] = (__bf16)a.y; pv[2] = (__bf16)a.z; pv[3] = (__bf16)a.w;
    pv[4] = (__bf16)b.x; pv[5] = (__bf16)b.y; pv[6] = (__bf16)b.z; pv[7] = (__bf16)b.w;
    *(bf16x8*)(out + (size_t)u * 8) = pv;
}

// W (R x O x I fp32) -> Bt frag-major bf16, half-contiguous unit order.
template<int I, int O>
__global__ void prep_w_kernel(const float* __restrict__ W, __bf16* __restrict__ Bt) {
    constexpr int NCH = I >> 7;
    const int u    = blockIdx.x * 256 + threadIdx.x;     // < NCH*2048
    const int r    = blockIdx.y;
    const int nb   = blockIdx.z;
    const int lane = u & 63;
    const int g    = (u >> 6) & 15;
    const int h    = (u >> 10) & 1;
    const int c    = u >> 11;
    const int mi   = g >> 1;
    const int ks   = (h << 1) + (g & 1);
    const int row  = nb * 128 + mi * 16 + (lane & 15);
    const int i    = c * 128 + ks * 32 + ((lane >> 4) << 3);
    const float* src = W + ((size_t)r * O + row) * I + i;
    const float4 a = *(const float4*)src;
    const float4 b = *(const float4*)(src + 4);
    bf16x8 pv;
    pv[0] = (__bf16)a.x; pv[1] = (__bf16)a.y; pv[2] = (__bf16)a.z; pv[3] = (__bf16)a.w;
    pv[4] = (__bf16)b.x; pv[5] = (__bf16)b.y; pv[6] = (__bf16)b.z; pv[7] = (__bf16)b.w;
    *(bf16x8*)(Bt + ((((size_t)nb * 9 + r) * NCH + c) * 2048 + (u & 2047)) * 8) = pv;
}

// bias tiles: per nb one 128x64 tile, 16 frags (f = ni*2 + ks2)
template<int O>
__global__ void prep_bias_kernel(const float* __restrict__ b, __bf16* __restrict__ BtB) {
    const int u    = blockIdx.x * 256 + threadIdx.x;     // < (O/128)*1024
    const int nb   = u >> 10;
    const int q    = u & 1023;
    const int lane = q & 63;
    const int f    = q >> 6;
    const int row  = nb * 128 + ((f >> 1) << 4) + (lane & 15);
    const int kb   = ((f & 1) << 5) + ((lane >> 4) << 3);
    bf16x8 pv;
#pragma unroll
    for (int e = 0; e < 8; ++e) {
        const int k = kb + e;
        pv[e] = (k < 9) ? (__bf16)b[(size_t)k * O + row] : (__bf16)0.f;
    }
    *(bf16x8*)(BtB + (size_t)u * 8) = pv;
}

// ---------------------------------------------------------------------------
// Relation-mixed GEMM, MERGED PHASE (one barrier per r) + r13 fused-fold math:
//   y[n,o] = sum_r e[n,r]*(sum_i x[n,i] W[r,o,i]) + sum_r e[n,r] b[r,o]
// Per 128-col i-chunk: af[4][4] global->VGPR once; prologue stages {0,1,2,3}.
// Phase r (9 per chunk): vmcnt(8 at r=0, else 0: outstanding = pair staged a
// full phase ago) -> ONE barrier -> issue stages {2r+2,2r+3} into the pair
// read LAST phase (readers retired before this barrier: MFMA operand
// lgkmcnt waits precede it in program order) -> h0: read bv, acc2 chains ->
// h1: read bv (regs reused), t-chains seeded by acc2, fused fold
// acc[m][n] += e_r * t. 64 MFMAs per barrier instead of 32; registers
// identical to r13 (128 arch + 128 acc, the proven-fit budget).
// ---------------------------------------------------------------------------
template<int I, int O, bool RELU, bool OUTF32>
__global__ __launch_bounds__(256, 2)
void kg_gemm(const __bf16* __restrict__ A, const float* __restrict__ E,
             const __bf16* __restrict__ Bt, const __bf16* __restrict__ BtB,
             void* __restrict__ Outv) {
    constexpr int NCH = I >> 7;
    constexpr int NBN = O >> 7;
    static_assert((I & 127) == 0 && (O & 127) == 0, "tile divisibility");

    __shared__ __align__(16) char lds[4 * 16384 + 4608];
    float* const ldsE = (float*)(lds + 65536);   // Et[r][row]

    const int tid  = threadIdx.x;
    const int nwg  = gridDim.x;
    const int braw = blockIdx.x;
    const int bid  = (braw & 7) * (nwg >> 3) + (braw >> 3);   // XCD swizzle (nwg%8==0)
    const int rb   = bid / NBN;
    const int nb   = bid % NBN;
    const int bm0  = rb << 7;
    const int bn0  = nb << 7;
    const int lane = tid & 63;
    const int wid  = tid >> 6;
    const int wr   = (wid >> 1) << 6;
    const int wc   = (wid & 1) << 6;
    const int l15  = lane & 15;
    const int lq   = lane >> 4;

    if (tid < 128) {
        const float* e = E + (size_t)(bm0 + tid) * 9;
#pragma unroll
        for (int q = 0; q < 9; ++q) ldsE[q * 128 + tid] = e[q];
    }
    // drain ldsE writes once; first chunk-top barrier publishes them
    asm volatile("s_waitcnt lgkmcnt(0)" ::: "memory");

    f32x4 acc[4][4];
#pragma unroll
    for (int m = 0; m < 4; ++m)
#pragma unroll
        for (int n = 0; n < 4; ++n)
            acc[m][n] = f32x4{0.f, 0.f, 0.f, 0.f};
    const f32x4 zero4 = {0.f, 0.f, 0.f, 0.f};

    const size_t Abase = (size_t)rb * NCH * 2048;       // units
    const size_t Bbase = (size_t)nb * 9 * NCH * 2048;   // units
    const int afb = (wr >> 4) << 2;   // A frag base
    const int nfb = (wc >> 4) << 1;   // B g base

    // stage sub-phase s (r=s>>1, h=s&1) into buf[s&3]  (4 loads/thread)
    auto stageS = [&](int s, int c) {
        const __bf16* src = Bt + (Bbase + ((size_t)(s >> 1) * NCH + c) * 2048
                                  + (size_t)((s & 1) << 10)) * 8;
        char* dst = lds + ((s & 3) << 14);
#pragma unroll
        for (int it = 0; it < 4; ++it) {
            const int q = it * 256 + tid;
            GLOAD_LDS16(src + (size_t)q * 8, dst + q * 16);
        }
    };

#pragma unroll 1
    for (int c = 0; c < NCH; ++c) {
        // chunk-top barrier: all waves past their last reads of prev chunk
        __builtin_amdgcn_s_barrier();
        __builtin_amdgcn_sched_barrier(0);
        // A fragments: global -> VGPR, once per chunk (oldest vm ops)
        bf16x8 af[4][4];
        {
            const __bf16* Ab = A + (Abase + (size_t)c * 2048) * 8;
#pragma unroll
            for (int m = 0; m < 4; ++m)
#pragma unroll
                for (int ks = 0; ks < 4; ++ks)
                    af[m][ks] = *(const bf16x8*)(Ab + ((size_t)((afb + (m << 2) + ks) << 6) + lane) * 8);
        }
        stageS(0, c); stageS(1, c); stageS(2, c); stageS(3, c);

#pragma unroll 1
        for (int r = 0; r < 9; ++r) {
            // wait: r=0 -> af + stages{0,1} done, {2,3} in flight;
            // r>=1 -> outstanding = exactly stages{2r,2r+1} (issued a full
            // phase ago, L2-hot) -> drain is ~free.
            if (r == 0) asm volatile("s_waitcnt vmcnt(8)" ::: "memory");
            else        asm volatile("s_waitcnt vmcnt(0)" ::: "memory");
            __builtin_amdgcn_s_barrier();
            __builtin_amdgcn_sched_barrier(0);
            // refill the pair read LAST phase (its readers retired pre-barrier)
            if (r >= 1 && r <= 7) { stageS(2 * r + 2, c); stageS(2 * r + 3, c); }

            f32x4 acc2[4][4];
            // ---- h = 0: build acc2 for this relation ----
            {
                const char* bp = lds + (((2 * r) & 3) << 14);
                bf16x8 bv[4][2];
#pragma unroll
                for (int n = 0; n < 4; ++n)
#pragma unroll
                    for (int j = 0; j < 2; ++j)
                        bv[n][j] = *(const bf16x8*)(bp + (((nfb + 2 * n + j) << 6) + lane) * 16);
#pragma unroll
                for (int m = 0; m < 4; ++m)
#pragma unroll
                    for (int n = 0; n < 4; ++n) {
                        f32x4 t = __builtin_amdgcn_mfma_f32_16x16x32_bf16(
                            af[m][0], bv[n][0], zero4, 0, 0, 0);
                        acc2[m][n] = __builtin_amdgcn_mfma_f32_16x16x32_bf16(
                            af[m][1], bv[n][1], t, 0, 0, 0);
                    }
            }
            // ---- h = 1: finish acc2 and FUSE the fold into each chain ----
            {
                const char* bp = lds + (((2 * r + 1) & 3) << 14);
                bf16x8 bv[4][2];
#pragma unroll
                for (int n = 0; n < 4; ++n)
#pragma unroll
                    for (int j = 0; j < 2; ++j)
                        bv[n][j] = *(const bf16x8*)(bp + (((nfb + 2 * n + j) << 6) + lane) * 16);
#pragma unroll
                for (int m = 0; m < 4; ++m) {
                    const f32x4 evm = *(const f32x4*)(ldsE + r * 128 + wr + m * 16 + lq * 4);
#pragma unroll
                    for (int n = 0; n < 4; ++n) {
                        f32x4 t = __builtin_amdgcn_mfma_f32_16x16x32_bf16(
                            af[m][2], bv[n][0], acc2[m][n], 0, 0, 0);
                        t = __builtin_amdgcn_mfma_f32_16x16x32_bf16(
                            af[m][3], bv[n][1], t, 0, 0, 0);
#pragma unroll
                        for (int j = 0; j < 4; ++j)
                            acc[m][n][j] += evm[j] * t[j];
                    }
                }
            }
        }
    }

    // ---- bias K=64 step: A-cols = e (built from ldsE), B = BtB tile
    __syncthreads();   // full drain; guards buffer overwrite
    {
        char* const bufB = lds;            // 16 KB
        char* const bufA = lds + 16384;    // 16 KB
#pragma unroll
        for (int rr = 0; rr < 4; ++rr) {
            const int q = rr * 256 + tid;
            GLOAD_LDS16(BtB + ((size_t)nb * 1024 + q) * 8, bufB + q * 16);
        }
#pragma unroll
        for (int rr = 0; rr < 4; ++rr) {
            const int q    = rr * 256 + tid;
            const int ln   = q & 63;
            const int f    = q >> 6;                       // ni*2 + ks2
            const int row  = ((f >> 1) << 4) + (ln & 15);
            const int kb   = ((f & 1) << 5) + ((ln >> 4) << 3);
            bf16x8 pv;
#pragma unroll
            for (int e8 = 0; e8 < 8; ++e8) {
                const int k = kb + e8;
                pv[e8] = (k < 9) ? (__bf16)ldsE[k * 128 + row] : (__bf16)0.f;
            }
            *(bf16x8*)(bufA + q * 16) = pv;
        }
        __syncthreads();
#pragma unroll
        for (int ks = 0; ks < 2; ++ks) {
            bf16x8 av[4], bv[4];
#pragma unroll
            for (int m = 0; m < 4; ++m)
                av[m] = *(const bf16x8*)(bufA + (((((wr >> 4) + m) * 2 + ks) << 6) + lane) * 16);
#pragma unroll
            for (int n = 0; n < 4; ++n)
                bv[n] = *(const bf16x8*)(bufB + (((((wc >> 4) + n) * 2 + ks) << 6) + lane) * 16);
#pragma unroll
            for (int m = 0; m < 4; ++m)
#pragma unroll
                for (int n = 0; n < 4; ++n)
                    acc[m][n] = __builtin_amdgcn_mfma_f32_16x16x32_bf16(
                        av[m], bv[n], acc[m][n], 0, 0, 0);
        }
    }

    // ---- epilogue: C/D layout col = l15, row = lq*4 + j
    if (OUTF32) {
        const int orow0 = bm0 + wr + lq * 4;
        const int ocol0 = bn0 + wc + l15;
#pragma unroll
        for (int m = 0; m < 4; ++m)
#pragma unroll
            for (int n = 0; n < 4; ++n)
#pragma unroll
                for (int j = 0; j < 4; ++j) {
                    float v = acc[m][n][j];
                    if (RELU) v = fmaxf(v, 0.f);
                    ((float*)Outv)[(size_t)(orow0 + m * 16 + j) * O + (ocol0 + n * 16)] = v;
                }
    } else {
        // write next layer's A in frag-major (I' = O)
        constexpr int NCHn = O >> 7;
        __bf16* outp = (__bf16*)Outv;
#pragma unroll
        for (int m = 0; m < 4; ++m) {
#pragma unroll
            for (int n = 0; n < 4; ++n) {
                const int col  = bn0 + wc + n * 16 + l15;
                const int c2   = col >> 7;
                const int f2   = (((wr >> 4) + m) << 2) + ((col >> 5) & 3);
                const int ln2  = ((col >> 3) & 3) * 16 + lq * 4;
                const size_t base =
                    (((size_t)rb * NCHn + c2) * 2048 + f2 * 64 + ln2) * 8 + (col & 7);
#pragma unroll
                for (int j = 0; j < 4; ++j) {
                    float v = acc[m][n][j];
                    if (RELU) v = fmaxf(v, 0.f);
                    outp[base + (size_t)j * 8] = (__bf16)v;
                }
            }
        }
    }
}

// ---------------------------------------------------------------------------
extern "C" void kernel_launch(void* const* d_in, const int* in_sizes, int n_in,
                              void* d_out, int out_size, void* d_ws, size_t ws_size,
                              hipStream_t stream) {
    const float* x  = (const float*)d_in[0];
    const float* E  = (const float*)d_in[1];
    const float* W0 = (const float*)d_in[2];
    const float* b0 = (const float*)d_in[3];
    const float* W1 = (const float*)d_in[4];
    const float* b1 = (const float*)d_in[5];
    const float* W2 = (const float*)d_in[6];
    const float* b2 = (const float*)d_in[7];
    const float* W3 = (const float*)d_in[8];
    const float* b3 = (const float*)d_in[9];

    char* ws = (char*)d_ws;
    const size_t actBytes = (size_t)65536 * 512 * 2;           // 64 MiB each
    __bf16* actA = (__bf16*)ws;
    __bf16* actB = (__bf16*)(ws + actBytes);
    char* p = ws + 2 * actBytes;
    __bf16* Bt0 = (__bf16*)p; p += (size_t)4 * 9 * 2 * 2048 * 16;
    __bf16* Bt1 = (__bf16*)p; p += (size_t)4 * 9 * 4 * 2048 * 16;
    __bf16* Bt2 = (__bf16*)p; p += (size_t)4 * 9 * 4 * 2048 * 16;
    __bf16* Bt3 = (__bf16*)p; p += (size_t)2 * 9 * 4 * 2048 * 16;
    __bf16* BtB0 = (__bf16*)p; p += (size_t)4 * 1024 * 16;
    __bf16* BtB1 = (__bf16*)p; p += (size_t)4 * 1024 * 16;
    __bf16* BtB2 = (__bf16*)p; p += (size_t)4 * 1024 * 16;
    __bf16* BtB3 = (__bf16*)p; p += (size_t)2 * 1024 * 16;
    if (ws_size < (size_t)(p - ws)) return;   // ws too small -> visible failure

    // prep (frag-major; Bt half-contiguous)
    cvt_x_kernel<<<dim3(8192), dim3(256), 0, stream>>>(x, actA);
    prep_w_kernel<256, 512><<<dim3(16, 9, 4), dim3(256), 0, stream>>>(W0, Bt0);
    prep_w_kernel<512, 512><<<dim3(32, 9, 4), dim3(256), 0, stream>>>(W1, Bt1);
    prep_w_kernel<512, 512><<<dim3(32, 9, 4), dim3(256), 0, stream>>>(W2, Bt2);
    prep_w_kernel<512, 256><<<dim3(32, 9, 2), dim3(256), 0, stream>>>(W3, Bt3);
    prep_bias_kernel<512><<<dim3(16), dim3(256), 0, stream>>>(b0, BtB0);
    prep_bias_kernel<512><<<dim3(16), dim3(256), 0, stream>>>(b1, BtB1);
    prep_bias_kernel<512><<<dim3(16), dim3(256), 0, stream>>>(b2, BtB2);
    prep_bias_kernel<256><<<dim3(8),  dim3(256), 0, stream>>>(b3, BtB3);

    // 4 fused layers
    kg_gemm<256, 512, true,  false><<<dim3(2048), dim3(256), 0, stream>>>(actA, E, Bt0, BtB0, actB);
    kg_gemm<512, 512, true,  false><<<dim3(2048), dim3(256), 0, stream>>>(actB, E, Bt1, BtB1, actA);
    kg_gemm<512, 512, true,  false><<<dim3(2048), dim3(256), 0, stream>>>(actA, E, Bt2, BtB2, actB);
    kg_gemm<512, 256, false, true ><<<dim3(1024), dim3(256), 0, stream>>>(actB, E, Bt3, BtB3, d_out);
}